// Round 1
// baseline (3129.354 us; speedup 1.0000x reference)
//
#include <hip/hip_runtime.h>

#define DIM 128
#define TM 64

// --- transpose W1 [128,128] and W2 [128,256] into w1t[k*128+j]=W1[j,k], w2t[k*128+j]=W2[j,k] ---
__global__ void k_transpose_w(const float* __restrict__ W1, const float* __restrict__ W2,
                              float* __restrict__ w1t, float* __restrict__ w2t) {
    int idx = blockIdx.x * 256 + threadIdx.x;       // 192*256 = 49152 exactly
    if (idx < 16384) {
        int k = idx >> 7, j = idx & 127;
        w1t[k * 128 + j] = W1[j * 128 + k];
    } else {
        int i = idx - 16384;                        // < 32768
        int k = i >> 7, j = i & 127;
        w2t[k * 128 + j] = W2[j * 256 + k];
    }
}

__global__ void k_zero(float4* __restrict__ p, int n4) {
    int idx = blockIdx.x * 256 + threadIdx.x;
    if (idx < n4) p[idx] = make_float4(0.f, 0.f, 0.f, 0.f);
}

// --- agg[row[e]] += val[e] * input[col[e]]  (linearity: W1 applied afterwards as GEMM) ---
__global__ void k_scatter(const float4* __restrict__ in4, const int* __restrict__ er,
                          const int* __restrict__ ec, const float* __restrict__ ev,
                          float* __restrict__ agg, int E) {
    int idx = blockIdx.x * 256 + threadIdx.x;
    int e = idx >> 5, l = idx & 31;                 // 32 lanes (float4 each) per edge
    if (e >= E) return;
    int r = er[e], c = ec[e];
    float v = ev[e];
    float4 x = in4[c * 32 + l];
    float* d = agg + r * DIM + l * 4;
    unsafeAtomicAdd(d + 0, v * x.x);
    unsafeAtomicAdd(d + 1, v * x.y);
    unsafeAtomicAdd(d + 2, v * x.z);
    unsafeAtomicAdd(d + 3, v * x.w);
}

// --- in-place: io rows <- io rows @ W1^T  (agg -> neigh) ---
__global__ __launch_bounds__(256) void k_gemm1(float* __restrict__ io,
                                               const float* __restrict__ w1t, int N) {
    __shared__ float sW[16384];                     // 64 KB: full W1^T
    {
        const float4* w4 = (const float4*)w1t;
        float4* s4w = (float4*)sW;
        for (int i = threadIdx.x; i < 4096; i += 256) s4w[i] = w4[i];
    }
    __syncthreads();
    int tj = threadIdx.x & 15, ti = threadIdx.x >> 4;
    int r0 = blockIdx.x * TM + ti * 4;
    int j0 = tj * 8;
    float acc[4][8];
#pragma unroll
    for (int i = 0; i < 4; ++i)
#pragma unroll
        for (int j = 0; j < 8; ++j) acc[i][j] = 0.f;

    const float4* a4 = (const float4*)io;
    const float4* s4 = (const float4*)sW;
    for (int k4 = 0; k4 < 32; ++k4) {
        float4 a[4];
#pragma unroll
        for (int i = 0; i < 4; ++i) {
            int r = r0 + i;
            a[i] = (r < N) ? a4[r * 32 + k4] : make_float4(0.f, 0.f, 0.f, 0.f);
        }
#pragma unroll
        for (int s = 0; s < 4; ++s) {
            int k = k4 * 4 + s;
            float4 w0 = s4[k * 32 + tj * 2];
            float4 w1 = s4[k * 32 + tj * 2 + 1];
#pragma unroll
            for (int i = 0; i < 4; ++i) {
                float av = ((const float*)&a[i])[s];
                acc[i][0] += av * w0.x; acc[i][1] += av * w0.y;
                acc[i][2] += av * w0.z; acc[i][3] += av * w0.w;
                acc[i][4] += av * w1.x; acc[i][5] += av * w1.y;
                acc[i][6] += av * w1.z; acc[i][7] += av * w1.w;
            }
        }
    }
    __syncthreads();        // all in-place reads complete before any writes
    float4* o4 = (float4*)io;
#pragma unroll
    for (int i = 0; i < 4; ++i) {
        int r = r0 + i;
        if (r < N) {
            o4[r * 32 + tj * 2]     = make_float4(acc[i][0], acc[i][1], acc[i][2], acc[i][3]);
            o4[r * 32 + tj * 2 + 1] = make_float4(acc[i][4], acc[i][5], acc[i][6], acc[i][7]);
        }
    }
}

// --- in-place: io rows <- leaky_relu([x+nb, x*nb] @ W2^T), nb = io rows ---
__global__ __launch_bounds__(256) void k_gemm2(const float* __restrict__ in,
                                               float* __restrict__ io,
                                               const float* __restrict__ w2t, int N) {
    __shared__ float sW[16384];                     // 64 KB: one K-half of W2^T
    int tj = threadIdx.x & 15, ti = threadIdx.x >> 4;
    int r0 = blockIdx.x * TM + ti * 4;
    const float4* in4 = (const float4*)in;
    const float4* nb4 = (const float4*)io;
    float acc[4][8];
#pragma unroll
    for (int i = 0; i < 4; ++i)
#pragma unroll
        for (int j = 0; j < 8; ++j) acc[i][j] = 0.f;

    for (int half = 0; half < 2; ++half) {
        __syncthreads();    // protect LDS overwrite (no-op cost first iter)
        {
            const float4* w4 = (const float4*)(w2t + half * 16384);
            float4* s4w = (float4*)sW;
            for (int i = threadIdx.x; i < 4096; i += 256) s4w[i] = w4[i];
        }
        __syncthreads();
        const float4* s4 = (const float4*)sW;
        for (int k4 = 0; k4 < 32; ++k4) {
            float4 h[4];
#pragma unroll
            for (int i = 0; i < 4; ++i) {
                int r = r0 + i;
                if (r < N) {
                    float4 x = in4[r * 32 + k4];
                    float4 nb = nb4[r * 32 + k4];
                    h[i] = (half == 0)
                         ? make_float4(x.x + nb.x, x.y + nb.y, x.z + nb.z, x.w + nb.w)
                         : make_float4(x.x * nb.x, x.y * nb.y, x.z * nb.z, x.w * nb.w);
                } else {
                    h[i] = make_float4(0.f, 0.f, 0.f, 0.f);
                }
            }
#pragma unroll
            for (int s = 0; s < 4; ++s) {
                int k = k4 * 4 + s;
                float4 w0 = s4[k * 32 + tj * 2];
                float4 w1 = s4[k * 32 + tj * 2 + 1];
#pragma unroll
                for (int i = 0; i < 4; ++i) {
                    float hv = ((const float*)&h[i])[s];
                    acc[i][0] += hv * w0.x; acc[i][1] += hv * w0.y;
                    acc[i][2] += hv * w0.z; acc[i][3] += hv * w0.w;
                    acc[i][4] += hv * w1.x; acc[i][5] += hv * w1.y;
                    acc[i][6] += hv * w1.z; acc[i][7] += hv * w1.w;
                }
            }
        }
    }
    __syncthreads();        // all in-place reads complete before any writes
    float4* o4 = (float4*)io;
#pragma unroll
    for (int i = 0; i < 4; ++i) {
        int r = r0 + i;
        if (r < N) {
#pragma unroll
            for (int j = 0; j < 8; ++j) {
                float t = acc[i][j];
                acc[i][j] = (t > 0.f) ? t : 0.01f * t;
            }
            o4[r * 32 + tj * 2]     = make_float4(acc[i][0], acc[i][1], acc[i][2], acc[i][3]);
            o4[r * 32 + tj * 2 + 1] = make_float4(acc[i][4], acc[i][5], acc[i][6], acc[i][7]);
        }
    }
}

extern "C" void kernel_launch(void* const* d_in, const int* in_sizes, int n_in,
                              void* d_out, int out_size, void* d_ws, size_t ws_size,
                              hipStream_t stream) {
    const float* input = (const float*)d_in[0];
    const int*   er    = (const int*)d_in[1];
    const int*   ec    = (const int*)d_in[2];
    const float* ev    = (const float*)d_in[3];
    const float* W1    = (const float*)d_in[4];
    const float* W2    = (const float*)d_in[5];
    int N = in_sizes[0] / DIM;      // 100000
    int E = in_sizes[1];            // 1600000
    float* out = (float*)d_out;     // reused as agg -> neigh -> final out (row-local, in-place)
    float* w1t = (float*)d_ws;      // 16384 floats
    float* w2t = w1t + 16384;       // 32768 floats (192 KB total ws use)

    k_transpose_w<<<192, 256, 0, stream>>>(W1, W2, w1t, w2t);

    int n4 = N * (DIM / 4);
    k_zero<<<(n4 + 255) / 256, 256, 0, stream>>>((float4*)out, n4);

    long long sthreads = (long long)E * 32;
    k_scatter<<<(int)((sthreads + 255) / 256), 256, 0, stream>>>(
        (const float4*)input, er, ec, ev, out, E);

    int nb = (N + TM - 1) / TM;
    k_gemm1<<<nb, 256, 0, stream>>>(out, w1t, N);
    k_gemm2<<<nb, 256, 0, stream>>>(input, out, w2t, N);
}

// Round 2
// 750.790 us; speedup vs baseline: 4.1681x; 4.1681x over previous
//
#include <hip/hip_runtime.h>

#define DIM 128
#define TM 64
#define N_SCAN_BS 256

// ---------------- weight transpose: w1t[k*128+j]=W1[j,k], w2t[k*128+j]=W2[j,k] ----------------
__global__ void k_transpose_w(const float* __restrict__ W1, const float* __restrict__ W2,
                              float* __restrict__ w1t, float* __restrict__ w2t) {
    int idx = blockIdx.x * 256 + threadIdx.x;       // 192*256 = 49152 exactly
    if (idx < 16384) {
        int k = idx >> 7, j = idx & 127;
        w1t[k * 128 + j] = W1[j * 128 + k];
    } else {
        int i = idx - 16384;                        // < 32768
        int k = i >> 7, j = i & 127;
        w2t[k * 128 + j] = W2[j * 256 + k];
    }
}

// ---------------- counting sort: hist -> scan -> ticket scatter ----------------
__global__ void k_init_counts(int* __restrict__ counts, int N) {
    int i = blockIdx.x * 256 + threadIdx.x;
    if (i < N) counts[i] = 0;
}

__global__ void k_hist(const int* __restrict__ er, int* __restrict__ counts, int E) {
    int i = blockIdx.x * 256 + threadIdx.x;
    if (i < E) atomicAdd(&counts[er[i]], 1);
}

// per-block inclusive scan; row_start holds block-local inclusive, bsum[b] = block total
__global__ __launch_bounds__(N_SCAN_BS) void k_scan1(const int* __restrict__ counts,
                                                     int* __restrict__ row_start,
                                                     int* __restrict__ bsum, int N) {
    __shared__ int s[N_SCAN_BS];
    int t = threadIdx.x, i = blockIdx.x * N_SCAN_BS + t;
    int v = (i < N) ? counts[i] : 0;
    s[t] = v;
    __syncthreads();
    for (int off = 1; off < N_SCAN_BS; off <<= 1) {
        int x = (t >= off) ? s[t - off] : 0;
        __syncthreads();
        s[t] += x;
        __syncthreads();
    }
    if (i < N) row_start[i] = s[t];
    if (t == N_SCAN_BS - 1) bsum[blockIdx.x] = s[t];
}

// single block: exclusive scan of block sums (nb1 <= 512)
__global__ __launch_bounds__(512) void k_scan2(const int* __restrict__ bsum,
                                               int* __restrict__ boff, int nb1) {
    __shared__ int s[512];
    int t = threadIdx.x;
    int v = (t < nb1) ? bsum[t] : 0;
    s[t] = v;
    __syncthreads();
    for (int off = 1; off < 512; off <<= 1) {
        int x = (t >= off) ? s[t - off] : 0;
        __syncthreads();
        s[t] += x;
        __syncthreads();
    }
    if (t < nb1) boff[t] = s[t] - v;    // exclusive
}

// finalize: global exclusive start; cursor = start (mutable ticket counter)
__global__ void k_scan3(const int* __restrict__ counts, int* __restrict__ row_start,
                        int* __restrict__ cursor, const int* __restrict__ boff, int N) {
    int i = blockIdx.x * 256 + threadIdx.x;
    if (i < N) {
        int excl = row_start[i] - counts[i] + boff[i >> 8];
        row_start[i] = excl;
        cursor[i] = excl;
    }
}

// scatter (col,val) into CSR order; afterwards cursor[r] == segment end
__global__ void k_scatter2(const int* __restrict__ er, const int* __restrict__ ec,
                           const float* __restrict__ ev, int* __restrict__ cursor,
                           int2* __restrict__ edata, int E) {
    int i = blockIdx.x * 256 + threadIdx.x;
    if (i < E) {
        int r = er[i];
        int pos = atomicAdd(&cursor[r], 1);
        edata[pos] = make_int2(ec[i], __float_as_int(ev[i]));
    }
}

// ---------------- gather: one wave per row, agg[row] = sum val * input[col] ----------------
__global__ __launch_bounds__(256) void k_gather(const float2* __restrict__ in2,
                                                const int2* __restrict__ edata,
                                                const int* __restrict__ row_start,
                                                const int* __restrict__ cursor,
                                                float2* __restrict__ agg2, int N) {
    int wave = threadIdx.x >> 6, lane = threadIdx.x & 63;
    int row = blockIdx.x * 4 + wave;
    if (row >= N) return;
    int beg = row_start[row], end = cursor[row];    // cursor holds end after scatter
    float2 acc = make_float2(0.f, 0.f);
    for (int p = beg; p < end; p += 64) {
        int nc = end - p; if (nc > 64) nc = 64;
        int2 ed = make_int2(0, 0);
        if (lane < nc) ed = edata[p + lane];
        for (int j = 0; j < nc; ++j) {
            int col = __shfl(ed.x, j);
            float v = __int_as_float(__shfl(ed.y, j));
            float2 x = in2[col * 64 + lane];
            acc.x += v * x.x;
            acc.y += v * x.y;
        }
    }
    agg2[row * 64 + lane] = acc;
}

// ---------------- in-place: io rows <- io rows @ W1^T  (agg -> neigh) ----------------
__global__ __launch_bounds__(256) void k_gemm1(float* __restrict__ io,
                                               const float* __restrict__ w1t, int N) {
    __shared__ float sW[16384];                     // 64 KB: full W1^T
    {
        const float4* w4 = (const float4*)w1t;
        float4* s4w = (float4*)sW;
        for (int i = threadIdx.x; i < 4096; i += 256) s4w[i] = w4[i];
    }
    __syncthreads();
    int tj = threadIdx.x & 15, ti = threadIdx.x >> 4;
    int r0 = blockIdx.x * TM + ti * 4;
    float acc[4][8];
#pragma unroll
    for (int i = 0; i < 4; ++i)
#pragma unroll
        for (int j = 0; j < 8; ++j) acc[i][j] = 0.f;

    const float4* a4 = (const float4*)io;
    const float4* s4 = (const float4*)sW;
    for (int k4 = 0; k4 < 32; ++k4) {
        float4 a[4];
#pragma unroll
        for (int i = 0; i < 4; ++i) {
            int r = r0 + i;
            a[i] = (r < N) ? a4[r * 32 + k4] : make_float4(0.f, 0.f, 0.f, 0.f);
        }
#pragma unroll
        for (int s = 0; s < 4; ++s) {
            int k = k4 * 4 + s;
            float4 w0 = s4[k * 32 + tj * 2];
            float4 w1 = s4[k * 32 + tj * 2 + 1];
#pragma unroll
            for (int i = 0; i < 4; ++i) {
                float av = ((const float*)&a[i])[s];
                acc[i][0] += av * w0.x; acc[i][1] += av * w0.y;
                acc[i][2] += av * w0.z; acc[i][3] += av * w0.w;
                acc[i][4] += av * w1.x; acc[i][5] += av * w1.y;
                acc[i][6] += av * w1.z; acc[i][7] += av * w1.w;
            }
        }
    }
    __syncthreads();        // all in-place reads complete before any writes
    float4* o4 = (float4*)io;
#pragma unroll
    for (int i = 0; i < 4; ++i) {
        int r = r0 + i;
        if (r < N) {
            o4[r * 32 + tj * 2]     = make_float4(acc[i][0], acc[i][1], acc[i][2], acc[i][3]);
            o4[r * 32 + tj * 2 + 1] = make_float4(acc[i][4], acc[i][5], acc[i][6], acc[i][7]);
        }
    }
}

// ---------------- in-place: io rows <- leaky_relu([x+nb, x*nb] @ W2^T) ----------------
__global__ __launch_bounds__(256) void k_gemm2(const float* __restrict__ in,
                                               float* __restrict__ io,
                                               const float* __restrict__ w2t, int N) {
    __shared__ float sW[16384];                     // 64 KB: one K-half of W2^T
    int tj = threadIdx.x & 15, ti = threadIdx.x >> 4;
    int r0 = blockIdx.x * TM + ti * 4;
    const float4* in4 = (const float4*)in;
    const float4* nb4 = (const float4*)io;
    float acc[4][8];
#pragma unroll
    for (int i = 0; i < 4; ++i)
#pragma unroll
        for (int j = 0; j < 8; ++j) acc[i][j] = 0.f;

    for (int half = 0; half < 2; ++half) {
        __syncthreads();    // protect LDS overwrite (no-op cost first iter)
        {
            const float4* w4 = (const float4*)(w2t + half * 16384);
            float4* s4w = (float4*)sW;
            for (int i = threadIdx.x; i < 4096; i += 256) s4w[i] = w4[i];
        }
        __syncthreads();
        const float4* s4 = (const float4*)sW;
        for (int k4 = 0; k4 < 32; ++k4) {
            float4 h[4];
#pragma unroll
            for (int i = 0; i < 4; ++i) {
                int r = r0 + i;
                if (r < N) {
                    float4 x = in4[r * 32 + k4];
                    float4 nb = nb4[r * 32 + k4];
                    h[i] = (half == 0)
                         ? make_float4(x.x + nb.x, x.y + nb.y, x.z + nb.z, x.w + nb.w)
                         : make_float4(x.x * nb.x, x.y * nb.y, x.z * nb.z, x.w * nb.w);
                } else {
                    h[i] = make_float4(0.f, 0.f, 0.f, 0.f);
                }
            }
#pragma unroll
            for (int s = 0; s < 4; ++s) {
                int k = k4 * 4 + s;
                float4 w0 = s4[k * 32 + tj * 2];
                float4 w1 = s4[k * 32 + tj * 2 + 1];
#pragma unroll
                for (int i = 0; i < 4; ++i) {
                    float hv = ((const float*)&h[i])[s];
                    acc[i][0] += hv * w0.x; acc[i][1] += hv * w0.y;
                    acc[i][2] += hv * w0.z; acc[i][3] += hv * w0.w;
                    acc[i][4] += hv * w1.x; acc[i][5] += hv * w1.y;
                    acc[i][6] += hv * w1.z; acc[i][7] += hv * w1.w;
                }
            }
        }
    }
    __syncthreads();        // all in-place reads complete before any writes
    float4* o4 = (float4*)io;
#pragma unroll
    for (int i = 0; i < 4; ++i) {
        int r = r0 + i;
        if (r < N) {
#pragma unroll
            for (int j = 0; j < 8; ++j) {
                float t = acc[i][j];
                acc[i][j] = (t > 0.f) ? t : 0.01f * t;
            }
            o4[r * 32 + tj * 2]     = make_float4(acc[i][0], acc[i][1], acc[i][2], acc[i][3]);
            o4[r * 32 + tj * 2 + 1] = make_float4(acc[i][4], acc[i][5], acc[i][6], acc[i][7]);
        }
    }
}

extern "C" void kernel_launch(void* const* d_in, const int* in_sizes, int n_in,
                              void* d_out, int out_size, void* d_ws, size_t ws_size,
                              hipStream_t stream) {
    const float* input = (const float*)d_in[0];
    const int*   er    = (const int*)d_in[1];
    const int*   ec    = (const int*)d_in[2];
    const float* ev    = (const float*)d_in[3];
    const float* W1    = (const float*)d_in[4];
    const float* W2    = (const float*)d_in[5];
    int N = in_sizes[0] / DIM;      // 100000
    int E = in_sizes[1];            // 1600000
    float* out = (float*)d_out;     // reused as agg -> neigh -> final out (row-local, in-place)

    // ---- workspace layout (ints) ----
    int* ws        = (int*)d_ws;
    int* counts    = ws;                    // N
    int* row_start = counts + N;            // N
    int* cursor    = row_start + N;         // N
    int* bsum      = cursor + N;            // <=512
    int* boff      = bsum + 512;            // <=512
    int2* edata    = (int2*)(ws + 3 * N + 1024);   // E int2 (3N+1024 even -> 8B aligned)
    float* w1t     = (float*)(edata + E);   // 16384 floats
    float* w2t     = w1t + 16384;           // 32768 floats

    k_transpose_w<<<192, 256, 0, stream>>>(W1, W2, w1t, w2t);

    // counting sort into CSR
    int nbN = (N + 255) / 256;              // 391
    int nbE = (E + 255) / 256;              // 6250
    k_init_counts<<<nbN, 256, 0, stream>>>(counts, N);
    k_hist<<<nbE, 256, 0, stream>>>(er, counts, E);
    k_scan1<<<nbN, N_SCAN_BS, 0, stream>>>(counts, row_start, bsum, N);
    k_scan2<<<1, 512, 0, stream>>>(bsum, boff, nbN);
    k_scan3<<<nbN, 256, 0, stream>>>(counts, row_start, cursor, boff, N);
    k_scatter2<<<nbE, 256, 0, stream>>>(er, ec, ev, cursor, edata, E);

    // gather: one wave per row
    k_gather<<<(N + 3) / 4, 256, 0, stream>>>(
        (const float2*)input, edata, row_start, cursor, (float2*)out, N);

    // dense epilogue GEMMs
    int nb = (N + TM - 1) / TM;
    k_gemm1<<<nb, 256, 0, stream>>>(out, w1t, N);
    k_gemm2<<<nb, 256, 0, stream>>>(input, out, w2t, N);
}

// Round 3
// 500.549 us; speedup vs baseline: 6.2518x; 1.4999x over previous
//
#include <hip/hip_runtime.h>

#define DIM 128
#define N_SCAN_BS 256

typedef __attribute__((ext_vector_type(8))) short short8;   // 8 x bf16 (4 VGPR)
typedef __attribute__((ext_vector_type(4))) float f32x4;    // 4 x f32  (4 VGPR)

__device__ __forceinline__ unsigned short f2bf(float f) {   // RNE fp32->bf16
    unsigned u = __float_as_uint(f);
    u += 0x7fffu + ((u >> 16) & 1u);
    return (unsigned short)(u >> 16);
}

// ---------------- prep: convert W1 [128,128] and W2 [128,256] to bf16 (no transpose:
// stored [n][k] row-major, exactly the B-fragment order: lane n=lq reads 8 contiguous k) ----
__global__ void k_prep(const float* __restrict__ W1, const float* __restrict__ W2,
                       unsigned short* __restrict__ w1b, unsigned short* __restrict__ w2b) {
    int idx = blockIdx.x * 256 + threadIdx.x;       // 192*256 = 49152 = 16384 + 32768
    if (idx < 16384)      w1b[idx] = f2bf(W1[idx]);
    else                  w2b[idx - 16384] = f2bf(W2[idx - 16384]);
}

// ---------------- counting sort: hist -> scan -> ticket scatter ----------------
__global__ void k_init_counts(int* __restrict__ counts, int N) {
    int i = blockIdx.x * 256 + threadIdx.x;
    if (i < N) counts[i] = 0;
}

__global__ void k_hist(const int* __restrict__ er, int* __restrict__ counts, int E) {
    int i = blockIdx.x * 256 + threadIdx.x;
    if (i < E) atomicAdd(&counts[er[i]], 1);
}

__global__ __launch_bounds__(N_SCAN_BS) void k_scan1(const int* __restrict__ counts,
                                                     int* __restrict__ row_start,
                                                     int* __restrict__ bsum, int N) {
    __shared__ int s[N_SCAN_BS];
    int t = threadIdx.x, i = blockIdx.x * N_SCAN_BS + t;
    int v = (i < N) ? counts[i] : 0;
    s[t] = v;
    __syncthreads();
    for (int off = 1; off < N_SCAN_BS; off <<= 1) {
        int x = (t >= off) ? s[t - off] : 0;
        __syncthreads();
        s[t] += x;
        __syncthreads();
    }
    if (i < N) row_start[i] = s[t];
    if (t == N_SCAN_BS - 1) bsum[blockIdx.x] = s[t];
}

__global__ __launch_bounds__(512) void k_scan2(const int* __restrict__ bsum,
                                               int* __restrict__ boff, int nb1) {
    __shared__ int s[512];
    int t = threadIdx.x;
    int v = (t < nb1) ? bsum[t] : 0;
    s[t] = v;
    __syncthreads();
    for (int off = 1; off < 512; off <<= 1) {
        int x = (t >= off) ? s[t - off] : 0;
        __syncthreads();
        s[t] += x;
        __syncthreads();
    }
    if (t < nb1) boff[t] = s[t] - v;    // exclusive
}

__global__ void k_scan3(const int* __restrict__ counts, int* __restrict__ row_start,
                        int* __restrict__ cursor, const int* __restrict__ boff, int N) {
    int i = blockIdx.x * 256 + threadIdx.x;
    if (i < N) {
        int excl = row_start[i] - counts[i] + boff[i >> 8];
        row_start[i] = excl;
        cursor[i] = excl;
    }
}

__global__ void k_scatter2(const int* __restrict__ er, const int* __restrict__ ec,
                           const float* __restrict__ ev, int* __restrict__ cursor,
                           int2* __restrict__ edata, int E) {
    int i = blockIdx.x * 256 + threadIdx.x;
    if (i < E) {
        int r = er[i];
        int pos = atomicAdd(&cursor[r], 1);
        edata[pos] = make_int2(ec[i], __float_as_int(ev[i]));
    }
}

// ---------------- gather: one wave per row, agg[row] = sum val * input[col] ----------------
__global__ __launch_bounds__(256) void k_gather(const float2* __restrict__ in2,
                                                const int2* __restrict__ edata,
                                                const int* __restrict__ row_start,
                                                const int* __restrict__ cursor,
                                                float2* __restrict__ agg2, int N) {
    int wave = threadIdx.x >> 6, lane = threadIdx.x & 63;
    int row = blockIdx.x * 4 + wave;
    if (row >= N) return;
    int beg = row_start[row], end = cursor[row];    // cursor holds end after scatter
    float2 acc = make_float2(0.f, 0.f);
    for (int p = beg; p < end; p += 64) {
        int nc = end - p; if (nc > 64) nc = 64;
        int2 ed = make_int2(0, 0);
        if (lane < nc) ed = edata[p + lane];
        for (int j = 0; j < nc; ++j) {
            int col = __shfl(ed.x, j);
            float v = __int_as_float(__shfl(ed.y, j));
            float2 x = in2[col * 64 + lane];
            acc.x += v * x.x;
            acc.y += v * x.y;
        }
    }
    agg2[row * 64 + lane] = acc;
}

// ---------------- fused MFMA: out = leaky_relu([x+agg@W1^T, x*(agg@W1^T)] @ W2^T) ----------
// Per block: 64 rows, 4 waves, each wave owns a 16-row strip end-to-end (in-place safe,
// no __syncthreads: LDS slabs are wave-private, used only for C-layout -> A-layout).
__global__ __launch_bounds__(256) void k_fused(const float* __restrict__ agg,
                                               const float* __restrict__ input,
                                               const unsigned short* __restrict__ w1b,
                                               const unsigned short* __restrict__ w2b,
                                               float* __restrict__ out, int N) {
    __shared__ __align__(16) unsigned short sh[2 * 64 * 136];   // h0 | h1, rows padded to 136
    int w = threadIdx.x >> 6, lane = threadIdx.x & 63;
    int quad = lane >> 4, lq = lane & 15;
    int m0 = blockIdx.x * 64 + w * 16;

    // ---- gemm1: neigh = agg @ W1^T (A from global fp32 -> bf16; B direct from global bf16) ----
    short8 afr[4];
    {
        int row = m0 + lq; if (row >= N) row = N - 1;
        const f32x4* a4 = (const f32x4*)(agg + (long)row * DIM);
#pragma unroll
        for (int kb = 0; kb < 4; ++kb) {
            f32x4 p = a4[kb * 8 + quad * 2];
            f32x4 q = a4[kb * 8 + quad * 2 + 1];
            short8 a;
            a[0] = (short)f2bf(p[0]); a[1] = (short)f2bf(p[1]);
            a[2] = (short)f2bf(p[2]); a[3] = (short)f2bf(p[3]);
            a[4] = (short)f2bf(q[0]); a[5] = (short)f2bf(q[1]);
            a[6] = (short)f2bf(q[2]); a[7] = (short)f2bf(q[3]);
            afr[kb] = a;
        }
    }
    f32x4 neigh[8];
#pragma unroll
    for (int nt = 0; nt < 8; ++nt) {
        f32x4 c = {0.f, 0.f, 0.f, 0.f};
#pragma unroll
        for (int kb = 0; kb < 4; ++kb) {
            short8 b = *(const short8*)(w1b + (nt * 16 + lq) * DIM + kb * 32 + quad * 8);
            c = __builtin_amdgcn_mfma_f32_16x16x32_bf16(afr[kb], b, c, 0, 0, 0);
        }
        neigh[nt] = c;
    }

    // ---- h phase: C-layout regs -> bf16 -> wave-private LDS rows (A-layout source) ----
    unsigned short* sh0 = sh;
    unsigned short* sh1 = sh + 64 * 136;
#pragma unroll
    for (int nt = 0; nt < 8; ++nt) {
#pragma unroll
        for (int rg = 0; rg < 4; ++rg) {
            int r = m0 + quad * 4 + rg;
            int rr = (r < N) ? r : (N - 1);
            float x = input[(long)rr * DIM + nt * 16 + lq];
            float nb = neigh[nt][rg];
            int off = (w * 16 + quad * 4 + rg) * 136 + nt * 16 + lq;
            sh0[off] = f2bf(x + nb);
            sh1[off] = f2bf(x * nb);
        }
    }

    // ---- gemm2 (K=256 over the two h halves) + leaky_relu epilogue, in-place store ----
    int arow = (w * 16 + lq) * 136;
#pragma unroll
    for (int nt = 0; nt < 8; ++nt) {
        f32x4 c = {0.f, 0.f, 0.f, 0.f};
#pragma unroll
        for (int kb = 0; kb < 4; ++kb) {
            short8 a = *(const short8*)(sh0 + arow + kb * 32 + quad * 8);
            short8 b = *(const short8*)(w2b + (nt * 16 + lq) * 256 + kb * 32 + quad * 8);
            c = __builtin_amdgcn_mfma_f32_16x16x32_bf16(a, b, c, 0, 0, 0);
        }
#pragma unroll
        for (int kb = 0; kb < 4; ++kb) {
            short8 a = *(const short8*)(sh1 + arow + kb * 32 + quad * 8);
            short8 b = *(const short8*)(w2b + (nt * 16 + lq) * 256 + 128 + kb * 32 + quad * 8);
            c = __builtin_amdgcn_mfma_f32_16x16x32_bf16(a, b, c, 0, 0, 0);
        }
#pragma unroll
        for (int rg = 0; rg < 4; ++rg) {
            int r = m0 + quad * 4 + rg;
            if (r < N) {
                float v = c[rg];
                v = (v > 0.f) ? v : 0.01f * v;
                out[(long)r * DIM + nt * 16 + lq] = v;
            }
        }
    }
}

extern "C" void kernel_launch(void* const* d_in, const int* in_sizes, int n_in,
                              void* d_out, int out_size, void* d_ws, size_t ws_size,
                              hipStream_t stream) {
    const float* input = (const float*)d_in[0];
    const int*   er    = (const int*)d_in[1];
    const int*   ec    = (const int*)d_in[2];
    const float* ev    = (const float*)d_in[3];
    const float* W1    = (const float*)d_in[4];
    const float* W2    = (const float*)d_in[5];
    int N = in_sizes[0] / DIM;      // 100000
    int E = in_sizes[1];            // 1600000
    float* out = (float*)d_out;     // agg (from gather) -> final out, in-place

    // ---- workspace layout ----
    int* ws        = (int*)d_ws;
    int* counts    = ws;                    // N
    int* row_start = counts + N;            // N
    int* cursor    = row_start + N;         // N
    int* bsum      = cursor + N;            // <=512
    int* boff      = bsum + 512;            // <=512
    int2* edata    = (int2*)(ws + 3 * N + 1024);        // E int2
    unsigned short* w1b = (unsigned short*)(edata + E); // 16384 bf16 (16B aligned)
    unsigned short* w2b = w1b + 16384;                  // 32768 bf16

    k_prep<<<192, 256, 0, stream>>>(W1, W2, w1b, w2b);

    // counting sort into CSR
    int nbN = (N + 255) / 256;              // 391
    int nbE = (E + 255) / 256;              // 6250
    k_init_counts<<<nbN, 256, 0, stream>>>(counts, N);
    k_hist<<<nbE, 256, 0, stream>>>(er, counts, E);
    k_scan1<<<nbN, N_SCAN_BS, 0, stream>>>(counts, row_start, bsum, N);
    k_scan2<<<1, 512, 0, stream>>>(bsum, boff, nbN);
    k_scan3<<<nbN, 256, 0, stream>>>(counts, row_start, cursor, boff, N);
    k_scatter2<<<nbE, 256, 0, stream>>>(er, ec, ev, cursor, edata, E);

    // gather: one wave per row
    k_gather<<<(N + 3) / 4, 256, 0, stream>>>(
        (const float2*)input, edata, row_start, cursor, (float2*)out, N);

    // fused MFMA epilogue: gemm1 + h + gemm2 + leaky_relu, in-place on out
    k_fused<<<(N + 63) / 64, 256, 0, stream>>>(out, input, w1b, w2b, out, N);
}